// Round 1
// baseline (1091.720 us; speedup 1.0000x reference)
//
#include <hip/hip_runtime.h>
#include <hip/hip_bf16.h>

#define HCH 4      // heads
#define F   128    // H*C
#define DIN 128
#define HID 128
#define NEG 0.2f

__device__ __forceinline__ float lrelu(float x){ return x > 0.f ? x : NEG * x; }

// order-preserving float->uint encoding (for atomicMax on signed floats)
__device__ __forceinline__ unsigned enc_f(float f){
    unsigned b = __float_as_uint(f);
    return (b & 0x80000000u) ? ~b : (b | 0x80000000u);
}
__device__ __forceinline__ float dec_f(unsigned k){
    unsigned b = (k & 0x80000000u) ? (k & 0x7FFFFFFFu) : ~k;
    return __uint_as_float(b);
}

// ---- K1: xl = x@Wl + bl ; xr = x@Wr + br  (8 rows per 128-thread block) ----
__global__ void k_transform(const float* __restrict__ x,
                            const float* __restrict__ Wl, const float* __restrict__ bl,
                            const float* __restrict__ Wr, const float* __restrict__ br,
                            float* __restrict__ xl, float* __restrict__ xr, int N){
    __shared__ float xs[8][DIN];
    const int j = threadIdx.x;
    const int base = blockIdx.x * 8;
    #pragma unroll
    for (int r = 0; r < 8; ++r){
        int row = base + r;
        xs[r][j] = (row < N) ? x[row * DIN + j] : 0.f;
    }
    __syncthreads();
    float accl[8], accr[8];
    const float blj = bl[j], brj = br[j];
    #pragma unroll
    for (int r = 0; r < 8; ++r){ accl[r] = blj; accr[r] = brj; }
    for (int k = 0; k < DIN; ++k){
        const float wl = Wl[k * F + j];
        const float wr = Wr[k * F + j];
        #pragma unroll
        for (int r = 0; r < 8; ++r){
            accl[r] = fmaf(xs[r][k], wl, accl[r]);
            accr[r] = fmaf(xs[r][k], wr, accr[r]);
        }
    }
    #pragma unroll
    for (int r = 0; r < 8; ++r){
        int row = base + r;
        if (row < N){ xl[row * F + j] = accl[r]; xr[row * F + j] = accr[r]; }
    }
}

// ---- K2: zero a region ----
__global__ void k_zero(float* __restrict__ p, long long n){
    long long t = (long long)blockIdx.x * blockDim.x + threadIdx.x;
    if (t < n) p[t] = 0.f;
}

// ---- K3: per-edge GATv2 score + segment max (wave per edge) ----
__global__ void k_edge_scores(const float* __restrict__ xl, const float* __restrict__ xr,
                              const int* __restrict__ ei, const float* __restrict__ att,
                              float* __restrict__ e_ws, unsigned* __restrict__ emax_enc,
                              int E, int Et){
    const int wid  = (int)(((long long)blockIdx.x * blockDim.x + threadIdx.x) >> 6);
    const int lane = threadIdx.x & 63;
    if (wid >= Et) return;
    int src, dst;
    if (wid < E){ src = ei[wid]; dst = ei[E + wid]; }
    else        { src = dst = wid - E; }
    const float2 xlv = ((const float2*)xl)[src * 64 + lane];
    const float2 xrv = ((const float2*)xr)[dst * 64 + lane];
    const float2 atv = ((const float2*)att)[lane];
    float a = lrelu(xlv.x + xrv.x);
    float b = lrelu(xlv.y + xrv.y);
    float s = atv.x * a + atv.y * b;
    // sum within each 16-lane group (one head spans lanes 16h..16h+15)
    s += __shfl_xor(s, 1, 64);
    s += __shfl_xor(s, 2, 64);
    s += __shfl_xor(s, 4, 64);
    s += __shfl_xor(s, 8, 64);
    if ((lane & 15) == 0){
        const int h = lane >> 4;
        e_ws[wid * HCH + h] = s;
        atomicMax(&emax_enc[dst * HCH + h], enc_f(s));
    }
}

// ---- K4: ee = exp(e - emax[dst]); denom += ee  (thread per edge*head) ----
__global__ void k_exp_denom(const int* __restrict__ ei, const unsigned* __restrict__ emax_enc,
                            float* __restrict__ e_ws, float* __restrict__ denom,
                            int E, int Et){
    const long long t = (long long)blockIdx.x * blockDim.x + threadIdx.x;
    if (t >= (long long)Et * HCH) return;
    const int edge = (int)(t >> 2);
    const int h    = (int)(t & 3);
    const int dst  = (edge < E) ? ei[E + edge] : (edge - E);
    const float m  = dec_f(emax_enc[dst * HCH + h]);
    const float ee = expf(e_ws[t] - m);
    e_ws[t] = ee;
    atomicAdd(&denom[dst * HCH + h], ee);
}

// ---- K5: out[dst] += alpha * xl[src]  (wave per edge) ----
__global__ void k_aggregate(const float* __restrict__ xl, const int* __restrict__ ei,
                            const float* __restrict__ e_ws, const float* __restrict__ denom,
                            float* __restrict__ outagg, int E, int Et){
    const int wid  = (int)(((long long)blockIdx.x * blockDim.x + threadIdx.x) >> 6);
    const int lane = threadIdx.x & 63;
    if (wid >= Et) return;
    int src, dst;
    if (wid < E){ src = ei[wid]; dst = ei[E + wid]; }
    else        { src = dst = wid - E; }
    const int h = lane >> 4;
    const float alpha = e_ws[wid * HCH + h] / (denom[dst * HCH + h] + 1e-16f);
    const float2 xlv = ((const float2*)xl)[src * 64 + lane];
    atomicAdd(&outagg[dst * F + 2 * lane],     alpha * xlv.x);
    atomicAdd(&outagg[dst * F + 2 * lane + 1], alpha * xlv.y);
}

// ---- K6: h = relu(out + bias); per-graph max-pool via uint atomicMax ----
__global__ void k_relu_pool(const float* __restrict__ outagg, const float* __restrict__ bias,
                            const int* __restrict__ batch, unsigned* __restrict__ g_bits, int N){
    const int t = blockIdx.x * blockDim.x + threadIdx.x;
    if (t >= N * F) return;
    const int i = t >> 7, j = t & 127;
    float hv = outagg[t] + bias[j];
    hv = hv > 0.f ? hv : 0.f;   // >= 0, so uint order == float order, init 0 ok
    atomicMax(&g_bits[batch[i] * F + j], __float_as_uint(hv));
}

// ---- K7: dueling heads, one block (128 thr) per graph ----
__global__ void k_dueling(const float* __restrict__ g,
                          const float* __restrict__ Wq1, const float* __restrict__ bq1,
                          const float* __restrict__ Wq2, const float* __restrict__ bq2,
                          const float* __restrict__ Wv1, const float* __restrict__ bv1,
                          const float* __restrict__ Wv2, const float* __restrict__ bv2,
                          float* __restrict__ out){
    __shared__ float gs[F], hq[HID], hv[HID], red0[128], red1[128], red2[128];
    const int t = threadIdx.x, gi = blockIdx.x;
    gs[t] = g[gi * F + t];
    __syncthreads();
    float aq = bq1[t], av = bv1[t];
    for (int k = 0; k < F; ++k){
        aq = fmaf(gs[k], Wq1[k * HID + t], aq);
        av = fmaf(gs[k], Wv1[k * HID + t], av);
    }
    hq[t] = aq > 0.f ? aq : 0.f;
    hv[t] = av > 0.f ? av : 0.f;
    __syncthreads();
    red0[t] = hq[t] * Wq2[t * 2 + 0];
    red1[t] = hq[t] * Wq2[t * 2 + 1];
    red2[t] = hv[t] * Wv2[t];
    __syncthreads();
    for (int off = 64; off > 0; off >>= 1){
        if (t < off){ red0[t] += red0[t + off]; red1[t] += red1[t + off]; red2[t] += red2[t + off]; }
        __syncthreads();
    }
    if (t == 0){
        const float q0 = red0[0] + bq2[0];
        const float q1 = red1[0] + bq2[1];
        const float v  = red2[0] + bv2[0];
        out[gi * 2 + 0] = 0.5f * (q0 - q1) + v;
        out[gi * 2 + 1] = 0.5f * (q1 - q0) + v;
    }
}

extern "C" void kernel_launch(void* const* d_in, const int* in_sizes, int n_in,
                              void* d_out, int out_size, void* d_ws, size_t ws_size,
                              hipStream_t stream) {
    const float* x    = (const float*)d_in[0];
    const float* Wl   = (const float*)d_in[1];
    const float* bl   = (const float*)d_in[2];
    const float* Wr   = (const float*)d_in[3];
    const float* br   = (const float*)d_in[4];
    const float* att  = (const float*)d_in[5];
    const float* bias = (const float*)d_in[6];
    const float* Wq1  = (const float*)d_in[7];
    const float* bq1  = (const float*)d_in[8];
    const float* Wq2  = (const float*)d_in[9];
    const float* bq2  = (const float*)d_in[10];
    const float* Wv1  = (const float*)d_in[11];
    const float* bv1  = (const float*)d_in[12];
    const float* Wv2  = (const float*)d_in[13];
    const float* bv2  = (const float*)d_in[14];
    const int*   ei   = (const int*)d_in[15];
    const int*   batch= (const int*)d_in[16];
    float* out = (float*)d_out;

    const int N  = in_sizes[0] / DIN;
    const int E  = in_sizes[15] / 2;
    const int Et = E + N;
    const int Gg = out_size / 2;

    // workspace layout (floats)
    float* ws = (float*)d_ws;
    float*    xl       = ws;                          // N*F
    float*    xr       = xl + (size_t)N * F;          // N*F
    float*    e_ws     = xr + (size_t)N * F;          // Et*HCH
    float*    zero_beg = e_ws + (size_t)Et * HCH;     // zero region starts here
    float*    outagg   = zero_beg;                    // N*F
    unsigned* emax_enc = (unsigned*)(outagg + (size_t)N * F);   // N*HCH
    float*    denom    = (float*)(emax_enc + (size_t)N * HCH);  // N*HCH
    unsigned* g_bits   = (unsigned*)(denom + (size_t)N * HCH);  // Gg*F
    const long long zero_n = (long long)N * F + (long long)N * HCH * 2 + (long long)Gg * F;

    // K1: linear transforms
    k_transform<<<(N + 7) / 8, 128, 0, stream>>>(x, Wl, bl, Wr, br, xl, xr, N);
    // K2: zero accumulators (emax encoded-0 == lowest key, ok since every node has a self loop)
    k_zero<<<(unsigned)((zero_n + 255) / 256), 256, 0, stream>>>(zero_beg, zero_n);
    // K3: edge scores + segment max
    {
        long long thr = (long long)Et * 64;
        k_edge_scores<<<(unsigned)((thr + 255) / 256), 256, 0, stream>>>(
            xl, xr, ei, att, e_ws, emax_enc, E, Et);
    }
    // K4: exp + denom
    {
        long long thr = (long long)Et * HCH;
        k_exp_denom<<<(unsigned)((thr + 255) / 256), 256, 0, stream>>>(
            ei, emax_enc, e_ws, denom, E, Et);
    }
    // K5: weighted aggregation
    {
        long long thr = (long long)Et * 64;
        k_aggregate<<<(unsigned)((thr + 255) / 256), 256, 0, stream>>>(
            xl, ei, e_ws, denom, outagg, E, Et);
    }
    // K6: relu + bias + global max pool
    k_relu_pool<<<(N * F + 255) / 256, 256, 0, stream>>>(outagg, bias, batch, g_bits, N);
    // K7: dueling MLP heads
    k_dueling<<<Gg, 128, 0, stream>>>((const float*)g_bits, Wq1, bq1, Wq2, bq2,
                                      Wv1, bv1, Wv2, bv2, out);
}

// Round 2
// 383.446 us; speedup vs baseline: 2.8471x; 2.8471x over previous
//
#include <hip/hip_runtime.h>
#include <hip/hip_bf16.h>

#define HCH 4      // heads
#define F   128    // H*C
#define DIN 128
#define HID 128
#define NEG 0.2f

__device__ __forceinline__ float lrelu(float x){ return x > 0.f ? x : NEG * x; }

// ---- K1: xl = x@Wl + bl ; xr = x@Wr + br  (8 rows per 128-thread block) ----
__global__ void k_transform(const float* __restrict__ x,
                            const float* __restrict__ Wl, const float* __restrict__ bl,
                            const float* __restrict__ Wr, const float* __restrict__ br,
                            float* __restrict__ xl, float* __restrict__ xr, int N){
    __shared__ float xs[8][DIN];
    const int j = threadIdx.x;
    const int base = blockIdx.x * 8;
    #pragma unroll
    for (int r = 0; r < 8; ++r){
        int row = base + r;
        xs[r][j] = (row < N) ? x[row * DIN + j] : 0.f;
    }
    __syncthreads();
    float accl[8], accr[8];
    const float blj = bl[j], brj = br[j];
    #pragma unroll
    for (int r = 0; r < 8; ++r){ accl[r] = blj; accr[r] = brj; }
    for (int k = 0; k < DIN; ++k){
        const float wl = Wl[k * F + j];
        const float wr = Wr[k * F + j];
        #pragma unroll
        for (int r = 0; r < 8; ++r){
            accl[r] = fmaf(xs[r][k], wl, accl[r]);
            accr[r] = fmaf(xs[r][k], wr, accr[r]);
        }
    }
    #pragma unroll
    for (int r = 0; r < 8; ++r){
        int row = base + r;
        if (row < N){ xl[row * F + j] = accl[r]; xr[row * F + j] = accr[r]; }
    }
}

// ---- init: deg=1 (self loop), cursor=0, g_bits=0, row_start[N]=Et ----
__global__ void k_init(unsigned* __restrict__ deg, unsigned* __restrict__ cursor,
                       unsigned* __restrict__ g_bits, unsigned* __restrict__ row_start,
                       int N, int GF, int Et){
    int t = blockIdx.x * blockDim.x + threadIdx.x;
    if (t < N){ deg[t] = 1u; cursor[t] = 0u; }
    if (t < GF) g_bits[t] = 0u;
    if (t == 0) row_start[N] = (unsigned)Et;
}

// ---- histogram of dst ----
__global__ void k_hist(const int* __restrict__ ei, unsigned* __restrict__ deg, int E){
    int t = blockIdx.x * blockDim.x + threadIdx.x;
    if (t < E) atomicAdd(&deg[ei[E + t]], 1u);
}

// ---- per-block sums of deg ----
__global__ void k_blocksum(const unsigned* __restrict__ deg, unsigned* __restrict__ bsum, int N){
    __shared__ unsigned lds[256];
    int t = threadIdx.x; int idx = blockIdx.x * 256 + t;
    lds[t] = (idx < N) ? deg[idx] : 0u; __syncthreads();
    for (int off = 128; off > 0; off >>= 1){ if (t < off) lds[t] += lds[t + off]; __syncthreads(); }
    if (t == 0) bsum[blockIdx.x] = lds[0];
}

// ---- exclusive scan of block sums (single 1024-thread block, NB<=1024) ----
__global__ void k_spine(const unsigned* __restrict__ bsum, unsigned* __restrict__ spine, int NB){
    __shared__ unsigned lds[1024];
    int t = threadIdx.x;
    unsigned v = (t < NB) ? bsum[t] : 0u;
    lds[t] = v; __syncthreads();
    unsigned acc = v;
    for (int off = 1; off < 1024; off <<= 1){
        unsigned add = (t >= off) ? lds[t - off] : 0u; __syncthreads();
        acc += add; lds[t] = acc; __syncthreads();
    }
    if (t < NB) spine[t] = acc - v;
}

// ---- per-block exclusive scan + spine offset -> row_start ----
__global__ void k_scan_add(const unsigned* __restrict__ deg, const unsigned* __restrict__ spine,
                           unsigned* __restrict__ row_start, int N){
    __shared__ unsigned lds[256];
    int t = threadIdx.x; int idx = blockIdx.x * 256 + t;
    unsigned v = (idx < N) ? deg[idx] : 0u;
    lds[t] = v; __syncthreads();
    unsigned acc = v;
    for (int off = 1; off < 256; off <<= 1){
        unsigned add = (t >= off) ? lds[t - off] : 0u; __syncthreads();
        acc += add; lds[t] = acc; __syncthreads();
    }
    if (idx < N) row_start[idx] = spine[blockIdx.x] + acc - v;
}

// ---- scatter edges into CSR (slot 0 of each row reserved for self loop) ----
__global__ void k_scatter(const int* __restrict__ ei, const unsigned* __restrict__ row_start,
                          unsigned* __restrict__ cursor, int* __restrict__ csr_src, int E){
    int t = blockIdx.x * blockDim.x + threadIdx.x;
    if (t >= E) return;
    int dst = ei[E + t];
    unsigned pos = row_start[dst] + 1u + atomicAdd(&cursor[dst], 1u);
    csr_src[pos] = ei[t];
}

// ---- fused per-node: scores + online softmax + aggregate + relu/bias + pool ----
__global__ void k_node(const float* __restrict__ xl, const float* __restrict__ xr,
                       const int* __restrict__ csr_src, const unsigned* __restrict__ row_start,
                       const float* __restrict__ att, const float* __restrict__ bias,
                       const int* __restrict__ batch, unsigned* __restrict__ g_bits, int N){
    const int wid  = (int)(((long long)blockIdx.x * blockDim.x + threadIdx.x) >> 6);
    const int lane = threadIdx.x & 63;
    if (wid >= N) return;
    const int i  = wid;
    const int rs = (int)row_start[i];
    const int re = (int)row_start[i + 1];
    const int deg = re - rs;
    const float2 xrv = ((const float2*)xr)[i * 64 + lane];
    const float2 atv = ((const float2*)att)[lane];
    // lane k holds src of edge k (k>=1); slot 0 is the self loop
    int my_src = (lane > 0 && rs + lane < re) ? csr_src[rs + lane] : i;
    float m = -3.0e38f, d = 0.f, ax = 0.f, ay = 0.f;
    for (int k = 0; k < deg; ++k){
        const int src = (k == 0) ? i : ((k < 64) ? __shfl(my_src, k, 64) : csr_src[rs + k]);
        const float2 xlv = ((const float2*)xl)[src * 64 + lane];
        float a = lrelu(xlv.x + xrv.x);
        float b = lrelu(xlv.y + xrv.y);
        float s = atv.x * a + atv.y * b;
        s += __shfl_xor(s, 1, 64);
        s += __shfl_xor(s, 2, 64);
        s += __shfl_xor(s, 4, 64);
        s += __shfl_xor(s, 8, 64);          // all 16 lanes of a head group now hold the score
        const float mn = fmaxf(m, s);
        const float sc = __expf(m - mn);
        const float p  = __expf(s - mn);
        d  = d * sc + p;
        ax = ax * sc + p * xlv.x;
        ay = ay * sc + p * xlv.y;
        m = mn;
    }
    const float inv = 1.f / (d + 1e-16f);
    const float2 bz = ((const float2*)bias)[lane];
    const float h0 = fmaxf(ax * inv + bz.x, 0.f);
    const float h1 = fmaxf(ay * inv + bz.y, 0.f);
    const int g = batch[i];
    atomicMax(&g_bits[g * F + 2 * lane],     __float_as_uint(h0));
    atomicMax(&g_bits[g * F + 2 * lane + 1], __float_as_uint(h1));
}

// ---- dueling heads, one block (128 thr) per graph ----
__global__ void k_dueling(const float* __restrict__ g,
                          const float* __restrict__ Wq1, const float* __restrict__ bq1,
                          const float* __restrict__ Wq2, const float* __restrict__ bq2,
                          const float* __restrict__ Wv1, const float* __restrict__ bv1,
                          const float* __restrict__ Wv2, const float* __restrict__ bv2,
                          float* __restrict__ out){
    __shared__ float gs[F], hq[HID], hv[HID], red0[128], red1[128], red2[128];
    const int t = threadIdx.x, gi = blockIdx.x;
    gs[t] = g[gi * F + t];
    __syncthreads();
    float aq = bq1[t], av = bv1[t];
    for (int k = 0; k < F; ++k){
        aq = fmaf(gs[k], Wq1[k * HID + t], aq);
        av = fmaf(gs[k], Wv1[k * HID + t], av);
    }
    hq[t] = aq > 0.f ? aq : 0.f;
    hv[t] = av > 0.f ? av : 0.f;
    __syncthreads();
    red0[t] = hq[t] * Wq2[t * 2 + 0];
    red1[t] = hq[t] * Wq2[t * 2 + 1];
    red2[t] = hv[t] * Wv2[t];
    __syncthreads();
    for (int off = 64; off > 0; off >>= 1){
        if (t < off){ red0[t] += red0[t + off]; red1[t] += red1[t + off]; red2[t] += red2[t + off]; }
        __syncthreads();
    }
    if (t == 0){
        const float q0 = red0[0] + bq2[0];
        const float q1 = red1[0] + bq2[1];
        const float v  = red2[0] + bv2[0];
        out[gi * 2 + 0] = 0.5f * (q0 - q1) + v;
        out[gi * 2 + 1] = 0.5f * (q1 - q0) + v;
    }
}

extern "C" void kernel_launch(void* const* d_in, const int* in_sizes, int n_in,
                              void* d_out, int out_size, void* d_ws, size_t ws_size,
                              hipStream_t stream) {
    const float* x    = (const float*)d_in[0];
    const float* Wl   = (const float*)d_in[1];
    const float* bl   = (const float*)d_in[2];
    const float* Wr   = (const float*)d_in[3];
    const float* br   = (const float*)d_in[4];
    const float* att  = (const float*)d_in[5];
    const float* bias = (const float*)d_in[6];
    const float* Wq1  = (const float*)d_in[7];
    const float* bq1  = (const float*)d_in[8];
    const float* Wq2  = (const float*)d_in[9];
    const float* bq2  = (const float*)d_in[10];
    const float* Wv1  = (const float*)d_in[11];
    const float* bv1  = (const float*)d_in[12];
    const float* Wv2  = (const float*)d_in[13];
    const float* bv2  = (const float*)d_in[14];
    const int*   ei   = (const int*)d_in[15];
    const int*   batch= (const int*)d_in[16];
    float* out = (float*)d_out;

    const int N  = in_sizes[0] / DIN;
    const int E  = in_sizes[15] / 2;
    const int Et = E + N;
    const int Gg = out_size / 2;
    const int GF = Gg * F;
    const int NB = (N + 255) / 256;

    // workspace layout
    float*    ws        = (float*)d_ws;
    float*    xl        = ws;                              // N*F
    float*    xr        = xl + (size_t)N * F;              // N*F
    unsigned* deg       = (unsigned*)(xr + (size_t)N * F); // N
    unsigned* cursor    = deg + N;                         // N
    unsigned* row_start = cursor + N;                      // N+1
    unsigned* bsum      = row_start + N + 1;               // NB
    unsigned* spine     = bsum + NB;                       // NB
    int*      csr_src   = (int*)(spine + NB);              // Et
    unsigned* g_bits    = (unsigned*)(csr_src + Et);       // GF

    // K1: linear transforms
    k_transform<<<(N + 7) / 8, 128, 0, stream>>>(x, Wl, bl, Wr, br, xl, xr, N);
    // init
    {
        int mx = N > GF ? N : GF;
        k_init<<<(mx + 255) / 256, 256, 0, stream>>>(deg, cursor, g_bits, row_start, N, GF, Et);
    }
    // CSR build
    k_hist<<<(E + 255) / 256, 256, 0, stream>>>(ei, deg, E);
    k_blocksum<<<NB, 256, 0, stream>>>(deg, bsum, N);
    k_spine<<<1, 1024, 0, stream>>>(bsum, spine, NB);
    k_scan_add<<<NB, 256, 0, stream>>>(deg, spine, row_start, N);
    k_scatter<<<(E + 255) / 256, 256, 0, stream>>>(ei, row_start, cursor, csr_src, E);
    // fused per-node GATv2 + pool
    {
        long long thr = (long long)N * 64;
        k_node<<<(unsigned)((thr + 255) / 256), 256, 0, stream>>>(
            xl, xr, csr_src, row_start, att, bias, batch, g_bits, N);
    }
    // dueling MLP heads
    k_dueling<<<Gg, 128, 0, stream>>>((const float*)g_bits, Wq1, bq1, Wq2, bq2,
                                      Wv1, bv1, Wv2, bv2, out);
}

// Round 3
// 322.771 us; speedup vs baseline: 3.3823x; 1.1880x over previous
//
#include <hip/hip_runtime.h>
#include <hip/hip_bf16.h>

#define HCH 4      // heads
#define F   128    // H*C
#define DIN 128
#define HID 128
#define NEG 0.2f

__device__ __forceinline__ float lrelu(float x){ return x > 0.f ? x : NEG * x; }

// ---- K1: xl = x@Wl + bl ; xr = x@Wr + br  (32 rows per 256-thread block) ----
__global__ void k_transform(const float* __restrict__ x,
                            const float* __restrict__ Wl, const float* __restrict__ bl,
                            const float* __restrict__ Wr, const float* __restrict__ br,
                            float* __restrict__ xl, float* __restrict__ xr, int N){
    __shared__ float xs[32][DIN];
    const int t = threadIdx.x;
    const int j = t & 127;
    const int half = t >> 7;
    const int base = blockIdx.x * 32;
    // stage 32 rows of x (float4 coalesced)
    {
        const float4* xg = (const float4*)(x + (size_t)base * DIN);
        float4* xsv = (float4*)&xs[0][0];
        #pragma unroll
        for (int q = 0; q < 4; ++q){
            int idx = t + q * 256;          // float4 index in 32x128 tile
            int row = idx >> 5;
            xsv[idx] = (base + row < N) ? xg[idx] : make_float4(0.f,0.f,0.f,0.f);
        }
    }
    __syncthreads();
    float accl[16], accr[16];
    const float blj = bl[j], brj = br[j];
    #pragma unroll
    for (int r = 0; r < 16; ++r){ accl[r] = blj; accr[r] = brj; }
    const int r0 = half * 16;
    #pragma unroll 2
    for (int k = 0; k < DIN; ++k){
        const float wl = Wl[k * F + j];
        const float wr = Wr[k * F + j];
        #pragma unroll
        for (int r = 0; r < 16; ++r){
            accl[r] = fmaf(xs[r0 + r][k], wl, accl[r]);
            accr[r] = fmaf(xs[r0 + r][k], wr, accr[r]);
        }
    }
    #pragma unroll
    for (int r = 0; r < 16; ++r){
        int row = base + r0 + r;
        if (row < N){ xl[row * F + j] = accl[r]; xr[row * F + j] = accr[r]; }
    }
}

// ---- init: deg=1 (self loop), cursor=0, g_bits=0, row_start[N]=Et ----
__global__ void k_init(unsigned* __restrict__ deg, unsigned* __restrict__ cursor,
                       unsigned* __restrict__ g_bits, unsigned* __restrict__ row_start,
                       int N, int GF, int Et){
    int t = blockIdx.x * blockDim.x + threadIdx.x;
    if (t < N){ deg[t] = 1u; cursor[t] = 0u; }
    if (t < GF) g_bits[t] = 0u;
    if (t == 0) row_start[N] = (unsigned)Et;
}

// ---- histogram of dst ----
__global__ void k_hist(const int* __restrict__ ei, unsigned* __restrict__ deg, int E){
    int t = blockIdx.x * blockDim.x + threadIdx.x;
    if (t < E) atomicAdd(&deg[ei[E + t]], 1u);
}

// ---- per-block sums of deg ----
__global__ void k_blocksum(const unsigned* __restrict__ deg, unsigned* __restrict__ bsum, int N){
    __shared__ unsigned lds[256];
    int t = threadIdx.x; int idx = blockIdx.x * 256 + t;
    lds[t] = (idx < N) ? deg[idx] : 0u; __syncthreads();
    for (int off = 128; off > 0; off >>= 1){ if (t < off) lds[t] += lds[t + off]; __syncthreads(); }
    if (t == 0) bsum[blockIdx.x] = lds[0];
}

// ---- exclusive scan of block sums (single 1024-thread block, NB<=1024) ----
__global__ void k_spine(const unsigned* __restrict__ bsum, unsigned* __restrict__ spine, int NB){
    __shared__ unsigned lds[1024];
    int t = threadIdx.x;
    unsigned v = (t < NB) ? bsum[t] : 0u;
    lds[t] = v; __syncthreads();
    unsigned acc = v;
    for (int off = 1; off < 1024; off <<= 1){
        unsigned add = (t >= off) ? lds[t - off] : 0u; __syncthreads();
        acc += add; lds[t] = acc; __syncthreads();
    }
    if (t < NB) spine[t] = acc - v;
}

// ---- per-block exclusive scan + spine offset -> row_start ----
__global__ void k_scan_add(const unsigned* __restrict__ deg, const unsigned* __restrict__ spine,
                           unsigned* __restrict__ row_start, int N){
    __shared__ unsigned lds[256];
    int t = threadIdx.x; int idx = blockIdx.x * 256 + t;
    unsigned v = (idx < N) ? deg[idx] : 0u;
    lds[t] = v; __syncthreads();
    unsigned acc = v;
    for (int off = 1; off < 256; off <<= 1){
        unsigned add = (t >= off) ? lds[t - off] : 0u; __syncthreads();
        acc += add; lds[t] = acc; __syncthreads();
    }
    if (idx < N) row_start[idx] = spine[blockIdx.x] + acc - v;
}

// ---- scatter edges into CSR (slot 0 of each row reserved for self loop) ----
__global__ void k_scatter(const int* __restrict__ ei, const unsigned* __restrict__ row_start,
                          unsigned* __restrict__ cursor, int* __restrict__ csr_src, int E){
    int t = blockIdx.x * blockDim.x + threadIdx.x;
    if (t >= E) return;
    int dst = ei[E + t];
    unsigned pos = row_start[dst] + 1u + atomicAdd(&cursor[dst], 1u);
    csr_src[pos] = ei[t];
}

// ---- fused per-node: scores + online softmax (4-way ILP) + aggregate + pool ----
__global__ void k_node(const float* __restrict__ xl, const float* __restrict__ xr,
                       const int* __restrict__ csr_src, const unsigned* __restrict__ row_start,
                       const float* __restrict__ att, const float* __restrict__ bias,
                       const int* __restrict__ batch, unsigned* __restrict__ g_bits, int N){
    const int wid  = (int)(((long long)blockIdx.x * blockDim.x + threadIdx.x) >> 6);
    const int lane = threadIdx.x & 63;
    if (wid >= N) return;
    const int i  = wid;
    const int rs = (int)row_start[i];
    const int re = (int)row_start[i + 1];
    const int deg = re - rs;
    const float2* __restrict__ xlp = (const float2*)xl;
    const float2 xrv = ((const float2*)xr)[i * 64 + lane];
    const float2 atv = ((const float2*)att)[lane];
    // lane k holds src of edge k (k>=1); slot 0 is the self loop
    const int my_src = (lane > 0 && rs + lane < re) ? csr_src[rs + lane] : i;

    float m0 = -3.0e38f, d0 = 0.f, ax0 = 0.f, ay0 = 0.f;
    float m1 = -3.0e38f, d1 = 0.f, ax1 = 0.f, ay1 = 0.f;
    float m2 = -3.0e38f, d2 = 0.f, ax2 = 0.f, ay2 = 0.f;
    float m3 = -3.0e38f, d3 = 0.f, ax3 = 0.f, ay3 = 0.f;

    // score from a pre-loaded source row -> fold into state
    auto proc = [&](float2 xlv, float& m_, float& d_, float& ax_, float& ay_){
        float a = lrelu(xlv.x + xrv.x);
        float b = lrelu(xlv.y + xrv.y);
        float s = fmaf(atv.x, a, atv.y * b);
        s += __shfl_xor(s, 1, 64);
        s += __shfl_xor(s, 2, 64);
        s += __shfl_xor(s, 4, 64);
        s += __shfl_xor(s, 8, 64);   // all 16 lanes of a head group hold the score
        const float mn = fmaxf(m_, s);
        const float sc = __expf(m_ - mn);
        const float p  = __expf(s - mn);
        d_  = d_ * sc + p;
        ax_ = fmaf(ax_, sc, p * xlv.x);
        ay_ = fmaf(ay_, sc, p * xlv.y);
        m_  = mn;
    };

    // self loop (edge 0)
    proc(xlp[i * 64 + lane], m0, d0, ax0, ay0);

    int k = 1;
    for (; k + 3 < deg; k += 4){
        const int s0 = (k     < 64) ? __shfl(my_src, k,     64) : csr_src[rs + k];
        const int s1 = (k + 1 < 64) ? __shfl(my_src, k + 1, 64) : csr_src[rs + k + 1];
        const int s2 = (k + 2 < 64) ? __shfl(my_src, k + 2, 64) : csr_src[rs + k + 2];
        const int s3 = (k + 3 < 64) ? __shfl(my_src, k + 3, 64) : csr_src[rs + k + 3];
        const float2 v0 = xlp[s0 * 64 + lane];
        const float2 v1 = xlp[s1 * 64 + lane];
        const float2 v2 = xlp[s2 * 64 + lane];
        const float2 v3 = xlp[s3 * 64 + lane];
        proc(v0, m0, d0, ax0, ay0);
        proc(v1, m1, d1, ax1, ay1);
        proc(v2, m2, d2, ax2, ay2);
        proc(v3, m3, d3, ax3, ay3);
    }
    for (; k < deg; ++k){
        const int s0 = (k < 64) ? __shfl(my_src, k, 64) : csr_src[rs + k];
        proc(xlp[s0 * 64 + lane], m0, d0, ax0, ay0);
    }

    // merge partial softmax states (empty states contribute exp(-inf)=0)
    auto merge = [&](float& m_, float& d_, float& ax_, float& ay_,
                     float mo, float do_, float axo, float ayo){
        const float mn = fmaxf(m_, mo);
        const float sa = __expf(m_ - mn);
        const float sb = __expf(mo - mn);
        d_  = d_ * sa + do_ * sb;
        ax_ = ax_ * sa + axo * sb;
        ay_ = ay_ * sa + ayo * sb;
        m_  = mn;
    };
    merge(m0, d0, ax0, ay0, m1, d1, ax1, ay1);
    merge(m2, d2, ax2, ay2, m3, d3, ax3, ay3);
    merge(m0, d0, ax0, ay0, m2, d2, ax2, ay2);

    const float inv = 1.f / (d0 + 1e-16f);
    const float2 bz = ((const float2*)bias)[lane];
    const float h0 = fmaxf(fmaf(ax0, inv, bz.x), 0.f);
    const float h1 = fmaxf(fmaf(ay0, inv, bz.y), 0.f);
    const int g = batch[i];
    atomicMax(&g_bits[g * F + 2 * lane],     __float_as_uint(h0));
    atomicMax(&g_bits[g * F + 2 * lane + 1], __float_as_uint(h1));
}

// ---- dueling heads, one block (128 thr) per graph ----
__global__ void k_dueling(const float* __restrict__ g,
                          const float* __restrict__ Wq1, const float* __restrict__ bq1,
                          const float* __restrict__ Wq2, const float* __restrict__ bq2,
                          const float* __restrict__ Wv1, const float* __restrict__ bv1,
                          const float* __restrict__ Wv2, const float* __restrict__ bv2,
                          float* __restrict__ out){
    __shared__ float gs[F], hq[HID], hv[HID], red0[128], red1[128], red2[128];
    const int t = threadIdx.x, gi = blockIdx.x;
    gs[t] = g[gi * F + t];
    __syncthreads();
    float aq = bq1[t], av = bv1[t];
    for (int k = 0; k < F; ++k){
        aq = fmaf(gs[k], Wq1[k * HID + t], aq);
        av = fmaf(gs[k], Wv1[k * HID + t], av);
    }
    hq[t] = aq > 0.f ? aq : 0.f;
    hv[t] = av > 0.f ? av : 0.f;
    __syncthreads();
    red0[t] = hq[t] * Wq2[t * 2 + 0];
    red1[t] = hq[t] * Wq2[t * 2 + 1];
    red2[t] = hv[t] * Wv2[t];
    __syncthreads();
    for (int off = 64; off > 0; off >>= 1){
        if (t < off){ red0[t] += red0[t + off]; red1[t] += red1[t + off]; red2[t] += red2[t + off]; }
        __syncthreads();
    }
    if (t == 0){
        const float q0 = red0[0] + bq2[0];
        const float q1 = red1[0] + bq2[1];
        const float v  = red2[0] + bv2[0];
        out[gi * 2 + 0] = 0.5f * (q0 - q1) + v;
        out[gi * 2 + 1] = 0.5f * (q1 - q0) + v;
    }
}

extern "C" void kernel_launch(void* const* d_in, const int* in_sizes, int n_in,
                              void* d_out, int out_size, void* d_ws, size_t ws_size,
                              hipStream_t stream) {
    const float* x    = (const float*)d_in[0];
    const float* Wl   = (const float*)d_in[1];
    const float* bl   = (const float*)d_in[2];
    const float* Wr   = (const float*)d_in[3];
    const float* br   = (const float*)d_in[4];
    const float* att  = (const float*)d_in[5];
    const float* bias = (const float*)d_in[6];
    const float* Wq1  = (const float*)d_in[7];
    const float* bq1  = (const float*)d_in[8];
    const float* Wq2  = (const float*)d_in[9];
    const float* bq2  = (const float*)d_in[10];
    const float* Wv1  = (const float*)d_in[11];
    const float* bv1  = (const float*)d_in[12];
    const float* Wv2  = (const float*)d_in[13];
    const float* bv2  = (const float*)d_in[14];
    const int*   ei   = (const int*)d_in[15];
    const int*   batch= (const int*)d_in[16];
    float* out = (float*)d_out;

    const int N  = in_sizes[0] / DIN;
    const int E  = in_sizes[15] / 2;
    const int Et = E + N;
    const int Gg = out_size / 2;
    const int GF = Gg * F;
    const int NB = (N + 255) / 256;

    // workspace layout
    float*    ws        = (float*)d_ws;
    float*    xl        = ws;                              // N*F
    float*    xr        = xl + (size_t)N * F;              // N*F
    unsigned* deg       = (unsigned*)(xr + (size_t)N * F); // N
    unsigned* cursor    = deg + N;                         // N
    unsigned* row_start = cursor + N;                      // N+1
    unsigned* bsum      = row_start + N + 1;               // NB
    unsigned* spine     = bsum + NB;                       // NB
    int*      csr_src   = (int*)(spine + NB);              // Et
    unsigned* g_bits    = (unsigned*)(csr_src + Et);       // GF

    // K1: linear transforms
    k_transform<<<(N + 31) / 32, 256, 0, stream>>>(x, Wl, bl, Wr, br, xl, xr, N);
    // init
    {
        int mx = N > GF ? N : GF;
        k_init<<<(mx + 255) / 256, 256, 0, stream>>>(deg, cursor, g_bits, row_start, N, GF, Et);
    }
    // CSR build
    k_hist<<<(E + 255) / 256, 256, 0, stream>>>(ei, deg, E);
    k_blocksum<<<NB, 256, 0, stream>>>(deg, bsum, N);
    k_spine<<<1, 1024, 0, stream>>>(bsum, spine, NB);
    k_scan_add<<<NB, 256, 0, stream>>>(deg, spine, row_start, N);
    k_scatter<<<(E + 255) / 256, 256, 0, stream>>>(ei, row_start, cursor, csr_src, E);
    // fused per-node GATv2 + pool
    {
        long long thr = (long long)N * 64;
        k_node<<<(unsigned)((thr + 255) / 256), 256, 0, stream>>>(
            xl, xr, csr_src, row_start, att, bias, batch, g_bits, N);
    }
    // dueling MLP heads
    k_dueling<<<Gg, 128, 0, stream>>>((const float*)g_bits, Wq1, bq1, Wq2, bq2,
                                      Wv1, bv1, Wv2, bv2, out);
}